// Round 4
// baseline (130.939 us; speedup 1.0000x reference)
//
#include <hip/hip_runtime.h>
#include <hip/hip_bf16.h>

#define B_  4
#define LQ  512
#define LK  512
#define D_  128
#define H_  128
#define TQ  4          // q-rows per attn block

#define TWO_LOG2E 2.885390081777927f   // 2*log2(e)
#define LOG2E     1.442695040888963f

__device__ __forceinline__ float fexp2(float x) {
#if __has_builtin(__builtin_amdgcn_exp2f)
  return __builtin_amdgcn_exp2f(x);     // v_exp_f32 (native exp2)
#else
  return exp2f(x);
#endif
}
__device__ __forceinline__ float frcp(float x) {
#if __has_builtin(__builtin_amdgcn_rcpf)
  return __builtin_amdgcn_rcpf(x);      // v_rcp_f32
#else
  return __fdividef(1.0f, x);
#endif
}

// 8 rows per block, 256 threads.
// Rows [0, B*LQ) -> qproj row-major [row][h].
// Rows [B*LQ, ..) -> kT TRANSPOSED [b][h][k] so the score kernel reads k
// contiguously (lane = k => coalesced). Outputs pre-scaled by 2*log2(e).
__global__ __launch_bounds__(256) void proj_kernel(
    const float* __restrict__ queries, const float* __restrict__ keys,
    const float* __restrict__ Wq, const float* __restrict__ Wk,
    float* __restrict__ qproj, float* __restrict__ kT) {
  __shared__ float s_x[8][D_];
  int r0 = blockIdx.x * 8;
  bool qside = r0 < B_ * LQ;
  const float* X = qside ? queries : keys;
  const float* W = qside ? Wq : Wk;
  int rb = qside ? r0 : r0 - B_ * LQ;
  int tid = threadIdx.x;
  for (int i = tid; i < 8 * D_; i += 256)
    s_x[i >> 7][i & 127] = X[(size_t)(rb + (i >> 7)) * D_ + (i & 127)];
  __syncthreads();
  int h = tid & 127, rh = tid >> 7;    // rh selects rows rh*4 .. rh*4+3
  float a0 = 0.f, a1 = 0.f, a2 = 0.f, a3 = 0.f;
  #pragma unroll 8
  for (int d = 0; d < D_; ++d) {
    float w = W[d * H_ + h];           // coalesced; W is L2-hot (64 KB)
    a0 += s_x[rh * 4 + 0][d] * w;      // LDS broadcasts
    a1 += s_x[rh * 4 + 1][d] * w;
    a2 += s_x[rh * 4 + 2][d] * w;
    a3 += s_x[rh * 4 + 3][d] * w;
  }
  if (qside) {
    qproj[(size_t)(rb + rh * 4 + 0) * H_ + h] = a0 * TWO_LOG2E;
    qproj[(size_t)(rb + rh * 4 + 1) * H_ + h] = a1 * TWO_LOG2E;
    qproj[(size_t)(rb + rh * 4 + 2) * H_ + h] = a2 * TWO_LOG2E;
    qproj[(size_t)(rb + rh * 4 + 3) * H_ + h] = a3 * TWO_LOG2E;
  } else {
    int b = rb >> 9, kk = (rb & 511) + rh * 4;   // LK = 512
    float* dst = kT + ((size_t)b * H_ + h) * LK + kk;
    dst[0] = a0 * TWO_LOG2E;   // scatter (64 lines/wave) — only 1 MB total, cheap
    dst[1] = a1 * TWO_LOG2E;
    dst[2] = a2 * TWO_LOG2E;
    dst[3] = a3 * TWO_LOG2E;
  }
}

// One block per (batch, TQ=4 q-rows). 512 threads = 8 waves.
__global__ __launch_bounds__(512, 4) void attn_kernel(
    const float* __restrict__ qproj, const float* __restrict__ kT,
    const float* __restrict__ values, const int* __restrict__ vlen_arr,
    const float* __restrict__ wv, const float* __restrict__ Wo,
    float* __restrict__ out) {
  int b  = blockIdx.y;
  int q0 = blockIdx.x * TQ;
  int tid = threadIdx.x;

  __shared__ float s_q[TQ][H_];        // pre-scaled q rows (2 KB)
  __shared__ float s_wv[H_];           // 0.5 KB
  __shared__ float s_sc[TQ][LK];       // scores -> weights (8 KB)
  __shared__ float s_po[2][TQ][D_];    // PV partials (4 KB)

  for (int i = tid; i < TQ * H_; i += 512)
    s_q[i >> 7][i & 127] = qproj[(size_t)(b * LQ + q0 + (i >> 7)) * H_ + (i & 127)];
  if (tid < H_) s_wv[tid] = wv[tid];
  __syncthreads();
  int vlen = vlen_arr[b];

  const float4* wv4p = (const float4*)s_wv;
  float sum_wv = 0.f;
  #pragma unroll
  for (int j = 0; j < H_ / 4; ++j) {
    float4 t = wv4p[j];
    sum_wv += t.x + t.y + t.z + t.w;
  }

  // ---- scores: thread (kt, qs) owns k = {2kt, 2kt+1} for q-rows {2qs, 2qs+1} ----
  // score = sum_wv - 2 * sum_h wv_h / (exp2(q'_h + k'_h) + 1)   [tanh identity]
  {
    int kt = tid & 255, qs = tid >> 8;
    int k  = kt * 2;
    if (k < vlen) {
      const float2* kTp = (const float2*)(kT + (size_t)b * H_ * LK);  // [h][k/2]
      const float4* qap = (const float4*)s_q[qs * 2 + 0];
      const float4* qbp = (const float4*)s_q[qs * 2 + 1];
      float a00 = 0.f, a10 = 0.f, a01 = 0.f, a11 = 0.f;  // a[kpt][ql]
      #pragma unroll 4
      for (int h4 = 0; h4 < H_ / 4; ++h4) {
        float2 kv0 = kTp[(size_t)(4 * h4 + 0) * 256 + kt];  // 512B/wave coalesced
        float2 kv1 = kTp[(size_t)(4 * h4 + 1) * 256 + kt];
        float2 kv2 = kTp[(size_t)(4 * h4 + 2) * 256 + kt];
        float2 kv3 = kTp[(size_t)(4 * h4 + 3) * 256 + kt];
        float4 w4 = wv4p[h4];       // LDS broadcast
        float4 qa = qap[h4];        // LDS broadcast
        float4 qb = qbp[h4];
        a00 = fmaf(w4.x, frcp(fexp2(qa.x + kv0.x) + 1.f), a00);
        a10 = fmaf(w4.x, frcp(fexp2(qa.x + kv0.y) + 1.f), a10);
        a01 = fmaf(w4.x, frcp(fexp2(qb.x + kv0.x) + 1.f), a01);
        a11 = fmaf(w4.x, frcp(fexp2(qb.x + kv0.y) + 1.f), a11);
        a00 = fmaf(w4.y, frcp(fexp2(qa.y + kv1.x) + 1.f), a00);
        a10 = fmaf(w4.y, frcp(fexp2(qa.y + kv1.y) + 1.f), a10);
        a01 = fmaf(w4.y, frcp(fexp2(qb.y + kv1.x) + 1.f), a01);
        a11 = fmaf(w4.y, frcp(fexp2(qb.y + kv1.y) + 1.f), a11);
        a00 = fmaf(w4.z, frcp(fexp2(qa.z + kv2.x) + 1.f), a00);
        a10 = fmaf(w4.z, frcp(fexp2(qa.z + kv2.y) + 1.f), a10);
        a01 = fmaf(w4.z, frcp(fexp2(qb.z + kv2.x) + 1.f), a01);
        a11 = fmaf(w4.z, frcp(fexp2(qb.z + kv2.y) + 1.f), a11);
        a00 = fmaf(w4.w, frcp(fexp2(qa.w + kv3.x) + 1.f), a00);
        a10 = fmaf(w4.w, frcp(fexp2(qa.w + kv3.y) + 1.f), a10);
        a01 = fmaf(w4.w, frcp(fexp2(qb.w + kv3.x) + 1.f), a01);
        a11 = fmaf(w4.w, frcp(fexp2(qb.w + kv3.y) + 1.f), a11);
      }
      bool m1 = (k + 1) < vlen;
      float2 r0 = { fmaf(-2.f, a00, sum_wv), m1 ? fmaf(-2.f, a10, sum_wv) : -1.0e6f };
      float2 r1 = { fmaf(-2.f, a01, sum_wv), m1 ? fmaf(-2.f, a11, sum_wv) : -1.0e6f };
      ((float2*)s_sc[qs * 2 + 0])[kt] = r0;
      ((float2*)s_sc[qs * 2 + 1])[kt] = r1;
    } else {
      float2 mm = { -1.0e6f, -1.0e6f };
      ((float2*)s_sc[qs * 2 + 0])[kt] = mm;
      ((float2*)s_sc[qs * 2 + 1])[kt] = mm;
    }
  }
  __syncthreads();

  int wave = tid >> 6, lane = tid & 63;

  // ---- masked softmax: wave w (w < TQ) handles q-row w ----
  if (wave < TQ) {
    float m = -3.0e38f;
    #pragma unroll
    for (int j = 0; j < LK / 64; ++j) m = fmaxf(m, s_sc[wave][lane + j * 64]);
    #pragma unroll
    for (int off = 32; off; off >>= 1) m = fmaxf(m, __shfl_xor(m, off));
    float sum = 0.f;
    float vals[LK / 64];
    #pragma unroll
    for (int j = 0; j < LK / 64; ++j) {
      float e = fexp2((s_sc[wave][lane + j * 64] - m) * LOG2E);  // masked -> 0
      vals[j] = e;
      sum += e;
    }
    #pragma unroll
    for (int off = 32; off; off >>= 1) sum += __shfl_xor(sum, off);
    float inv = frcp(sum);
    #pragma unroll
    for (int j = 0; j < LK / 64; ++j) s_sc[wave][lane + j * 64] = vals[j] * inv;
  }
  __syncthreads();

  // ---- PV: wave w -> (row = w>>1, k-chunk = w&1); float2 over d; bounded by vlen ----
  {
    int row = wave >> 1, kc = wave & 1;
    int kend = min((((vlen + 3) >> 2) << 2), (kc + 1) * 256);
    const float2* vrow = (const float2*)(values + (size_t)b * LK * D_);
    float2 a = {0.f, 0.f};
    for (int k = kc * 256; k < kend; k += 4) {
      float4 sc4 = *((const float4*)&s_sc[row][k]);   // LDS broadcast
      float2 v0 = vrow[(size_t)(k + 0) * 64 + lane];  // 512B/wave coalesced
      float2 v1 = vrow[(size_t)(k + 1) * 64 + lane];
      float2 v2 = vrow[(size_t)(k + 2) * 64 + lane];
      float2 v3 = vrow[(size_t)(k + 3) * 64 + lane];
      a.x += sc4.x * v0.x + sc4.y * v1.x + sc4.z * v2.x + sc4.w * v3.x;
      a.y += sc4.x * v0.y + sc4.y * v1.y + sc4.z * v2.y + sc4.w * v3.y;
    }
    s_po[kc][row][2 * lane]     = a.x;
    s_po[kc][row][2 * lane + 1] = a.y;
  }
  __syncthreads();

  // ---- output projection: 512 threads cover TQ*H outputs in one pass ----
  {
    int ql = tid >> 7, h = tid & 127;
    float acc = 0.f;
    #pragma unroll 8
    for (int d = 0; d < D_; ++d)
      acc += (s_po[0][ql][d] + s_po[1][ql][d]) * Wo[d * H_ + h];  // coalesced, L1/L2-hot
    out[((size_t)b * LQ + q0 + ql) * H_ + h] = acc;
  }
}

extern "C" void kernel_launch(void* const* d_in, const int* in_sizes, int n_in,
                              void* d_out, int out_size, void* d_ws, size_t ws_size,
                              hipStream_t stream) {
  const float* queries = (const float*)d_in[0];
  const float* keys    = (const float*)d_in[1];
  const float* values  = (const float*)d_in[2];
  const int*   vlen    = (const int*)d_in[3];
  const float* Wq      = (const float*)d_in[4];
  const float* Wk      = (const float*)d_in[5];
  const float* wv      = (const float*)d_in[6];
  const float* Wo      = (const float*)d_in[7];
  float* out = (float*)d_out;

  float* qproj = (float*)d_ws;                       // 1 MB, [row][h]
  float* kT    = qproj + (size_t)B_ * LQ * H_;       // 1 MB, [b][h][k]

  proj_kernel<<<dim3(B_ * (LQ + LK) / 8), 256, 0, stream>>>(queries, keys, Wq, Wk, qproj, kT);
  attn_kernel<<<dim3(LQ / TQ, B_), 512, 0, stream>>>(qproj, kT, values, vlen, wv, Wo, out);
}